// Round 3
// baseline (619.895 us; speedup 1.0000x reference)
//
#include <hip/hip_runtime.h>

#define BB 8
#define NN 20000
#define EE 320000
#define DD 64
#define ROWS (BB*NN)
#define EPS 1e-5f
#define CH 64  // readout chunks per batch

__device__ __forceinline__ int bcasti(int v, int l) {
  return __builtin_amdgcn_readlane(v, l);
}

// ---------------- encoder: h = relu(x @ W_in + b_in), D_IN=1, float4 ----------------
__global__ __launch_bounds__(256) void k_encoder(const float* __restrict__ x,
    const float* __restrict__ Win, const float* __restrict__ bin,
    float* __restrict__ h) {
  int idx = blockIdx.x * 256 + threadIdx.x;  // over ROWS*16 (4 d's each)
  int d4 = idx & 15;
  int r = idx >> 4;
  if (r < ROWS) {
    float xv = x[r];
    float4 wv = *(const float4*)&Win[d4 * 4];
    float4 bv = *(const float4*)&bin[d4 * 4];
    float4 o;
    o.x = fmaf(xv, wv.x, bv.x); o.x = o.x > 0.f ? o.x : 0.f;
    o.y = fmaf(xv, wv.y, bv.y); o.y = o.y > 0.f ? o.y : 0.f;
    o.z = fmaf(xv, wv.z, bv.z); o.z = o.z > 0.f ? o.z : 0.f;
    o.w = fmaf(xv, wv.w, bv.w); o.w = o.w > 0.f ? o.w : 0.f;
    *(float4*)&h[(size_t)r * DD + d4 * 4] = o;
  }
}

// ---------------- degree ----------------
__global__ __launch_bounds__(256) void k_deg(const int* __restrict__ dst,
                                             int* __restrict__ cnt) {
  int e = blockIdx.x * 256 + threadIdx.x;
  if (e < EE) atomicAdd(&cnt[dst[e]], 1);
}

__global__ __launch_bounds__(256) void k_invdeg(const int* __restrict__ cnt,
                                                float* __restrict__ invdeg) {
  int n = blockIdx.x * 256 + threadIdx.x;
  if (n < NN) {
    int c = cnt[n];
    invdeg[n] = 1.0f / (float)(c > 1 ? c : 1);
  }
}

// ---------------- exclusive scan of cnt -> rowptr (single block) ----------------
__global__ __launch_bounds__(1024) void k_scan(const int* __restrict__ cnt,
                                               int* __restrict__ rowptr) {
  __shared__ int part[1024];
  int t = threadIdx.x;
  const int PER = (NN + 1023) / 1024;  // 20
  int base = t * PER;
  int s = 0;
#pragma unroll
  for (int i = 0; i < PER; ++i) {
    int idx = base + i;
    s += (idx < NN) ? cnt[idx] : 0;
  }
  part[t] = s;
  __syncthreads();
  for (int off = 1; off < 1024; off <<= 1) {
    int v = (t >= off) ? part[t - off] : 0;
    __syncthreads();
    part[t] += v;
    __syncthreads();
  }
  int run = (t > 0) ? part[t - 1] : 0;
#pragma unroll
  for (int i = 0; i < PER; ++i) {
    int idx = base + i;
    if (idx <= NN) rowptr[idx] = run;
    run += (idx < NN) ? cnt[idx] : 0;
  }
}

// ---------------- fill CSR buckets: nbr[rowptr[dst]+k] = src ----------------
__global__ __launch_bounds__(256) void k_fill(const int* __restrict__ src,
    const int* __restrict__ dst, const int* __restrict__ rowptr,
    int* __restrict__ cur, int* __restrict__ nbr) {
  int e = blockIdx.x * 256 + threadIdx.x;
  if (e < EE) {
    int t = dst[e];
    int pos = rowptr[t] + atomicAdd(&cur[t], 1);
    nbr[pos] = src[e];
  }
}

// ---------------- pull aggregation: agg[b,n,:] = (sum_{s in N(n)} h[b,s,:]) * invdeg[n] ----------------
__global__ __launch_bounds__(256) void k_agg(const float* __restrict__ h,
    const int* __restrict__ rowptr, const int* __restrict__ nbr,
    const float* __restrict__ invdeg, float* __restrict__ agg) {
  int wid = (blockIdx.x * 256 + threadIdx.x) >> 6;  // wave per node
  int lane = threadIdx.x & 63;
  if (wid >= NN) return;
  int n = wid;
  int s0 = rowptr[n], s1 = rowptr[n + 1];
  float acc[BB];
#pragma unroll
  for (int b = 0; b < BB; ++b) acc[b] = 0.f;
  for (int base = s0; base < s1; base += 64) {
    int m = s1 - base;
    if (m > 64) m = 64;
    int idxv = (base + lane < s1) ? nbr[base + lane] : 0;
    int j = 0;
    // 4-edge unroll: 32 independent gather loads in flight
    for (; j + 4 <= m; j += 4) {
      int sA = bcasti(idxv, j), sB = bcasti(idxv, j + 1);
      int sC = bcasti(idxv, j + 2), sD = bcasti(idxv, j + 3);
      const float* pA = h + (size_t)sA * DD + lane;
      const float* pB = h + (size_t)sB * DD + lane;
      const float* pC = h + (size_t)sC * DD + lane;
      const float* pD = h + (size_t)sD * DD + lane;
      float vA[BB], vB[BB], vC[BB], vD[BB];
#pragma unroll
      for (int b = 0; b < BB; ++b) vA[b] = pA[(size_t)b * NN * DD];
#pragma unroll
      for (int b = 0; b < BB; ++b) vB[b] = pB[(size_t)b * NN * DD];
#pragma unroll
      for (int b = 0; b < BB; ++b) vC[b] = pC[(size_t)b * NN * DD];
#pragma unroll
      for (int b = 0; b < BB; ++b) vD[b] = pD[(size_t)b * NN * DD];
#pragma unroll
      for (int b = 0; b < BB; ++b) acc[b] += (vA[b] + vB[b]) + (vC[b] + vD[b]);
    }
    for (; j < m; ++j) {
      int s = bcasti(idxv, j);
      const float* hp = h + (size_t)s * DD + lane;
#pragma unroll
      for (int b = 0; b < BB; ++b) acc[b] += hp[(size_t)b * NN * DD];
    }
  }
  float iv = invdeg[n];
  float* ap = agg + (size_t)n * DD + lane;
#pragma unroll
  for (int b = 0; b < BB; ++b) ap[(size_t)b * NN * DD] = acc[b] * iv;
}

// ---------------- fused node update: scalar-broadcast GEMV + residual + LN ----------------
// z = h + relu(h@Ws + agg@Wm + bias); out = LayerNorm(z)
// Row index made wave-uniform via readfirstlane so h/agg row loads scalarize
// to s_load (SGPR-sourced v_fma). Weights held as per-lane columns in VGPRs;
// __launch_bounds__(256,2) allows the ~200-VGPR budget for residency.
__global__ __launch_bounds__(256, 2) void k_node(const float* __restrict__ h,
    const float* __restrict__ agg, const float* __restrict__ Ws,
    const float* __restrict__ Wm, const float* __restrict__ bias,
    const float* __restrict__ g, const float* __restrict__ be,
    float* __restrict__ hout, int nwaves_total) {
  int lane = threadIdx.x & 63;
  int w = __builtin_amdgcn_readfirstlane((int)(threadIdx.x >> 6));
  int gwave = __builtin_amdgcn_readfirstlane((int)blockIdx.x) * 4 + w;
  // per-lane weight column d=lane in registers (128 VGPR)
  float wsc[DD], wmc[DD];
#pragma unroll
  for (int k = 0; k < DD; ++k) {
    wsc[k] = Ws[k * DD + lane];
    wmc[k] = Wm[k * DD + lane];
  }
  float bv = bias[lane], gv = g[lane], bev = be[lane];
  for (int r = gwave; r < ROWS; r += nwaves_total) {
    const float* hrow = h + (size_t)r * DD;    // wave-uniform base
    const float* arow = agg + (size_t)r * DD;  // wave-uniform base
    float hv = hrow[lane];  // per-lane, for residual + LN
    float acc0 = 0.f, acc1 = 0.f, acc2 = 0.f, acc3 = 0.f;
#pragma unroll
    for (int c = 0; c < 4; ++c) {
      float hs[16], as_[16];
#pragma unroll
      for (int j = 0; j < 16; ++j) {
        hs[j] = hrow[c * 16 + j];   // uniform addr -> s_load
        as_[j] = arow[c * 16 + j];  // uniform addr -> s_load
      }
#pragma unroll
      for (int j = 0; j < 16; j += 2) {
        acc0 = fmaf(hs[j],      wsc[c * 16 + j],     acc0);
        acc1 = fmaf(as_[j],     wmc[c * 16 + j],     acc1);
        acc2 = fmaf(hs[j + 1],  wsc[c * 16 + j + 1], acc2);
        acc3 = fmaf(as_[j + 1], wmc[c * 16 + j + 1], acc3);
      }
    }
    float t = (acc0 + acc2) + (acc1 + acc3) + bv;
    float z = hv + (t > 0.f ? t : 0.f);
    // LayerNorm over the 64 lanes (= feature dim)
    float s = z;
#pragma unroll
    for (int off = 32; off > 0; off >>= 1) s += __shfl_xor(s, off, 64);
    float mu = s * (1.0f / 64.0f);
    float dz = z - mu;
    float v2 = dz * dz;
#pragma unroll
    for (int off = 32; off > 0; off >>= 1) v2 += __shfl_xor(v2, off, 64);
    float var = v2 * (1.0f / 64.0f);
    hout[(size_t)r * DD + lane] = fmaf(gv * dz, rsqrtf(var + EPS), bev);
  }
}

// ---------------- readout partials: per (b, chunk) sum & max over nodes ----------------
__global__ __launch_bounds__(256) void k_reduce(const float* __restrict__ h,
    float* __restrict__ psum, float* __restrict__ pmax) {
  int lane = threadIdx.x & 63;
  int w = threadIdx.x >> 6;
  int b = blockIdx.x / CH;
  int chunk = blockIdx.x % CH;
  const int csz = (NN + CH - 1) / CH;  // 313
  int n0 = chunk * csz;
  int n1 = n0 + csz;
  if (n1 > NN) n1 = NN;
  float s = 0.f, m = -INFINITY;
  for (int n = n0 + w; n < n1; n += 4) {
    float v = h[((size_t)b * NN + n) * DD + lane];
    s += v;
    m = fmaxf(m, v);
  }
  __shared__ float ls[4][DD], lm[4][DD];
  ls[w][lane] = s;
  lm[w][lane] = m;
  __syncthreads();
  if (w == 0) {
    float ss = ls[0][lane] + ls[1][lane] + ls[2][lane] + ls[3][lane];
    float mm = fmaxf(fmaxf(lm[0][lane], lm[1][lane]),
                     fmaxf(lm[2][lane], lm[3][lane]));
    psum[((size_t)b * CH + chunk) * DD + lane] = ss;
    pmax[((size_t)b * CH + chunk) * DD + lane] = mm;
  }
}

// ---------------- final: reduce partials, graph_emb, 2-layer MLP head ----------------
__global__ __launch_bounds__(512) void k_final(const float* __restrict__ psum,
    const float* __restrict__ pmax, const float* __restrict__ Wh1,
    const float* __restrict__ bh1, const float* __restrict__ Wh2,
    const float* __restrict__ bh2, float* __restrict__ out) {
  __shared__ float emb[BB][2 * DD];
  __shared__ float hid[BB][DD];
  int t = threadIdx.x;  // 512 threads = 8 b * 64 d
  int b = t >> 6, d = t & 63;
  float s = 0.f, m = -INFINITY;
  for (int c = 0; c < CH; ++c) {
    s += psum[((size_t)b * CH + c) * DD + d];
    m = fmaxf(m, pmax[((size_t)b * CH + c) * DD + d]);
  }
  emb[b][d] = s * (1.0f / (float)NN);
  emb[b][DD + d] = m;
  __syncthreads();
  float acc = bh1[d];
#pragma unroll
  for (int k = 0; k < 2 * DD; ++k) acc = fmaf(emb[b][k], Wh1[k * DD + d], acc);
  hid[b][d] = acc > 0.f ? acc : 0.f;
  __syncthreads();
  if (d == 0) {
    float o = bh2[0];
    for (int j = 0; j < DD; ++j) o = fmaf(hid[b][j], Wh2[j], o);
    out[b] = o;
  }
}

extern "C" void kernel_launch(void* const* d_in, const int* in_sizes, int n_in,
                              void* d_out, int out_size, void* d_ws, size_t ws_size,
                              hipStream_t stream) {
  const float* x    = (const float*)d_in[0];
  const int*   ei   = (const int*)d_in[1];
  const float* Win  = (const float*)d_in[2];
  const float* bin  = (const float*)d_in[3];
  const float* Ws1  = (const float*)d_in[4];
  const float* Wm1  = (const float*)d_in[5];
  const float* bias1= (const float*)d_in[6];
  const float* g1   = (const float*)d_in[7];
  const float* be1  = (const float*)d_in[8];
  const float* Ws2  = (const float*)d_in[9];
  const float* Wm2  = (const float*)d_in[10];
  const float* bias2= (const float*)d_in[11];
  const float* g2   = (const float*)d_in[12];
  const float* be2  = (const float*)d_in[13];
  const float* Wh1  = (const float*)d_in[14];
  const float* bh1  = (const float*)d_in[15];
  const float* Wh2  = (const float*)d_in[16];
  const float* bh2  = (const float*)d_in[17];
  float* out = (float*)d_out;

  const int* src = ei;
  const int* dst = ei + EE;

  char* ws = (char*)d_ws;
  size_t off = 0;
  auto carve = [&](size_t bytes) {
    void* p = ws + off;
    off = (off + bytes + 255) & ~(size_t)255;
    return p;
  };
  const size_t hbytes = sizeof(float) * (size_t)ROWS * DD;  // 40.96 MB
  float* hA     = (float*)carve(hbytes);
  float* hB     = (float*)carve(hbytes);
  float* agg    = (float*)carve(hbytes);
  int*   cnt    = (int*)carve(sizeof(int) * NN);      // also reused as 'cur'
  int*   rowptr = (int*)carve(sizeof(int) * (NN + 1));
  int*   nbr    = (int*)carve(sizeof(int) * EE);
  float* invdeg = (float*)carve(sizeof(float) * NN);
  float* psum   = (float*)carve(sizeof(float) * (size_t)BB * CH * DD);
  float* pmax   = (float*)carve(sizeof(float) * (size_t)BB * CH * DD);

  const int NODE_BLOCKS = 1024;
  const int NODE_WAVES = NODE_BLOCKS * 4;

  // encoder
  k_encoder<<<(ROWS * 16 + 255) / 256, 256, 0, stream>>>(x, Win, bin, hA);

  // CSR build (once; shared by both layers)
  hipMemsetAsync(cnt, 0, sizeof(int) * NN, stream);
  k_deg<<<(EE + 255) / 256, 256, 0, stream>>>(dst, cnt);
  k_invdeg<<<(NN + 255) / 256, 256, 0, stream>>>(cnt, invdeg);
  k_scan<<<1, 1024, 0, stream>>>(cnt, rowptr);
  hipMemsetAsync(cnt, 0, sizeof(int) * NN, stream);  // reuse as cursor
  k_fill<<<(EE + 255) / 256, 256, 0, stream>>>(src, dst, rowptr, cnt, nbr);

  // ---- layer 1 ----
  k_agg<<<(NN + 3) / 4, 256, 0, stream>>>(hA, rowptr, nbr, invdeg, agg);
  k_node<<<NODE_BLOCKS, 256, 0, stream>>>(hA, agg, Ws1, Wm1, bias1, g1, be1,
                                          hB, NODE_WAVES);

  // ---- layer 2 ----
  k_agg<<<(NN + 3) / 4, 256, 0, stream>>>(hB, rowptr, nbr, invdeg, agg);
  k_node<<<NODE_BLOCKS, 256, 0, stream>>>(hB, agg, Ws2, Wm2, bias2, g2, be2,
                                          hA, NODE_WAVES);

  // ---- readout + head ----
  k_reduce<<<BB * CH, 256, 0, stream>>>(hA, psum, pmax);
  k_final<<<1, 512, 0, stream>>>(psum, pmax, Wh1, bh1, Wh2, bh2, out);
}

// Round 4
// 508.886 us; speedup vs baseline: 1.2181x; 1.2181x over previous
//
#include <hip/hip_runtime.h>

#define BB 8
#define NN 20000
#define EE 320000
#define DD 64
#define ROWS (BB*NN)
#define EPS 1e-5f
#define CH 64  // readout chunks per batch

// Node-major layout: hN[n][b][d] -> flat index n*512 + b*64 + d.
// Row (b,n) == contiguous 64 floats at (n*8+b)*64.

__device__ __forceinline__ float bcastf(float v, int l) {
  return __uint_as_float(__builtin_amdgcn_readlane(__float_as_uint(v), l));
}
__device__ __forceinline__ int bcasti(int v, int l) {
  return __builtin_amdgcn_readlane(v, l);
}

// ---------------- encoder: hN = relu(x @ W_in + b_in), D_IN=1, float4 ----------------
__global__ __launch_bounds__(256) void k_encoder(const float* __restrict__ x,
    const float* __restrict__ Win, const float* __restrict__ bin,
    float* __restrict__ hN) {
  int idx = blockIdx.x * 256 + threadIdx.x;  // one float4 of hN each
  int g = idx * 4;                            // flat float index
  if (g < NN * 512) {
    int n = g >> 9;
    int b = (g >> 6) & 7;
    int d0 = g & 63;
    float xv = x[(size_t)b * NN + n];
    float4 wv = *(const float4*)&Win[d0];
    float4 bv = *(const float4*)&bin[d0];
    float4 o;
    o.x = fmaf(xv, wv.x, bv.x); o.x = o.x > 0.f ? o.x : 0.f;
    o.y = fmaf(xv, wv.y, bv.y); o.y = o.y > 0.f ? o.y : 0.f;
    o.z = fmaf(xv, wv.z, bv.z); o.z = o.z > 0.f ? o.z : 0.f;
    o.w = fmaf(xv, wv.w, bv.w); o.w = o.w > 0.f ? o.w : 0.f;
    *(float4*)&hN[g] = o;
  }
}

// ---------------- degree ----------------
__global__ __launch_bounds__(256) void k_deg(const int* __restrict__ dst,
                                             int* __restrict__ cnt) {
  int e = blockIdx.x * 256 + threadIdx.x;
  if (e < EE) atomicAdd(&cnt[dst[e]], 1);
}

__global__ __launch_bounds__(256) void k_invdeg(const int* __restrict__ cnt,
                                                float* __restrict__ invdeg) {
  int n = blockIdx.x * 256 + threadIdx.x;
  if (n < NN) {
    int c = cnt[n];
    invdeg[n] = 1.0f / (float)(c > 1 ? c : 1);
  }
}

// ---------------- exclusive scan of cnt -> rowptr (single block) ----------------
__global__ __launch_bounds__(1024) void k_scan(const int* __restrict__ cnt,
                                               int* __restrict__ rowptr) {
  __shared__ int part[1024];
  int t = threadIdx.x;
  const int PER = (NN + 1023) / 1024;  // 20
  int base = t * PER;
  int s = 0;
#pragma unroll
  for (int i = 0; i < PER; ++i) {
    int idx = base + i;
    s += (idx < NN) ? cnt[idx] : 0;
  }
  part[t] = s;
  __syncthreads();
  for (int off = 1; off < 1024; off <<= 1) {
    int v = (t >= off) ? part[t - off] : 0;
    __syncthreads();
    part[t] += v;
    __syncthreads();
  }
  int run = (t > 0) ? part[t - 1] : 0;
#pragma unroll
  for (int i = 0; i < PER; ++i) {
    int idx = base + i;
    if (idx <= NN) rowptr[idx] = run;
    run += (idx < NN) ? cnt[idx] : 0;
  }
}

// ---------------- fill CSR buckets: nbr[rowptr[dst]+k] = src ----------------
__global__ __launch_bounds__(256) void k_fill(const int* __restrict__ src,
    const int* __restrict__ dst, const int* __restrict__ rowptr,
    int* __restrict__ cur, int* __restrict__ nbr) {
  int e = blockIdx.x * 256 + threadIdx.x;
  if (e < EE) {
    int t = dst[e];
    int pos = rowptr[t] + atomicAdd(&cur[t], 1);
    nbr[pos] = src[e];
  }
}

// ---------------- pull aggregation, node-major ----------------
// aggN[n][b][d] = (sum_{s in N(n)} hN[s][b][d]) * invdeg[n]
// Per edge: one contiguous 2KB block -> 2x dwordx4 per lane, fully coalesced.
__global__ __launch_bounds__(256) void k_agg(const float* __restrict__ hN,
    const int* __restrict__ rowptr, const int* __restrict__ nbr,
    const float* __restrict__ invdeg, float* __restrict__ aggN) {
  int wid = (blockIdx.x * 256 + threadIdx.x) >> 6;  // wave per node
  int lane = threadIdx.x & 63;
  if (wid >= NN) return;
  int n = wid;
  int s0 = rowptr[n], s1 = rowptr[n + 1];
  float4 accLo = {0.f, 0.f, 0.f, 0.f}, accHi = {0.f, 0.f, 0.f, 0.f};
  for (int base = s0; base < s1; base += 64) {
    int m = s1 - base;
    if (m > 64) m = 64;
    int idxv = (base + lane < s1) ? nbr[base + lane] : 0;
    int j = 0;
    for (; j + 2 <= m; j += 2) {
      int sA = bcasti(idxv, j), sB = bcasti(idxv, j + 1);
      const float4* pA = (const float4*)(hN + (size_t)sA * 512);
      const float4* pB = (const float4*)(hN + (size_t)sB * 512);
      float4 a0 = pA[lane], a1 = pA[lane + 64];
      float4 b0 = pB[lane], b1 = pB[lane + 64];
      accLo.x += a0.x + b0.x; accLo.y += a0.y + b0.y;
      accLo.z += a0.z + b0.z; accLo.w += a0.w + b0.w;
      accHi.x += a1.x + b1.x; accHi.y += a1.y + b1.y;
      accHi.z += a1.z + b1.z; accHi.w += a1.w + b1.w;
    }
    if (j < m) {
      int sA = bcasti(idxv, j);
      const float4* pA = (const float4*)(hN + (size_t)sA * 512);
      float4 a0 = pA[lane], a1 = pA[lane + 64];
      accLo.x += a0.x; accLo.y += a0.y; accLo.z += a0.z; accLo.w += a0.w;
      accHi.x += a1.x; accHi.y += a1.y; accHi.z += a1.z; accHi.w += a1.w;
    }
  }
  float iv = invdeg[n];
  accLo.x *= iv; accLo.y *= iv; accLo.z *= iv; accLo.w *= iv;
  accHi.x *= iv; accHi.y *= iv; accHi.z *= iv; accHi.w *= iv;
  float4* q = (float4*)(aggN + (size_t)n * 512);
  q[lane] = accLo;
  q[lane + 64] = accHi;
}

// ---------------- fused node update: readlane GEMV + residual + LN ----------------
// Row index idx = n*8+b; row base = idx*64 (node-major).
// Weight columns pinned in VGPRs via opaque asm so they cannot be
// rematerialized as per-row L1 loads (round-2/3 showed VGPR=76 = streaming).
__global__ __launch_bounds__(256, 2) void k_node(const float* __restrict__ hN,
    const float* __restrict__ aggN, const float* __restrict__ Ws,
    const float* __restrict__ Wm, const float* __restrict__ bias,
    const float* __restrict__ g, const float* __restrict__ be,
    float* __restrict__ outN, int nwaves_total) {
  int lane = threadIdx.x & 63;
  int gwave = blockIdx.x * 4 + (threadIdx.x >> 6);
  float wsc[DD], wmc[DD];
#pragma unroll
  for (int k = 0; k < DD; ++k) {
    wsc[k] = Ws[k * DD + lane];
    wmc[k] = Wm[k * DD + lane];
  }
#pragma unroll
  for (int k = 0; k < DD; ++k) {
    asm volatile("" : "+v"(wsc[k]), "+v"(wmc[k]));  // pin in VGPRs
  }
  float bv = bias[lane], gv = g[lane], bev = be[lane];
  for (int r = gwave; r < ROWS; r += nwaves_total) {
    const float* hrow = hN + (size_t)r * DD;
    const float* arow = aggN + (size_t)r * DD;
    float hv = hrow[lane];
    float av = arow[lane];
    float acc0 = 0.f, acc1 = 0.f, acc2 = 0.f, acc3 = 0.f;
#pragma unroll
    for (int k = 0; k < DD; k += 2) {
      float h0 = bcastf(hv, k);
      float a0 = bcastf(av, k);
      float h1 = bcastf(hv, k + 1);
      float a1 = bcastf(av, k + 1);
      acc0 = fmaf(h0, wsc[k], acc0);
      acc1 = fmaf(a0, wmc[k], acc1);
      acc2 = fmaf(h1, wsc[k + 1], acc2);
      acc3 = fmaf(a1, wmc[k + 1], acc3);
    }
    float t = (acc0 + acc2) + (acc1 + acc3) + bv;
    float z = hv + (t > 0.f ? t : 0.f);
    // LayerNorm over the 64 lanes (= feature dim)
    float s = z;
#pragma unroll
    for (int off = 32; off > 0; off >>= 1) s += __shfl_xor(s, off, 64);
    float mu = s * (1.0f / 64.0f);
    float dz = z - mu;
    float v2 = dz * dz;
#pragma unroll
    for (int off = 32; off > 0; off >>= 1) v2 += __shfl_xor(v2, off, 64);
    float var = v2 * (1.0f / 64.0f);
    outN[(size_t)r * DD + lane] = fmaf(gv * dz, rsqrtf(var + EPS), bev);
  }
}

// ---------------- readout partials: per (b, chunk) sum & max over nodes ----------------
__global__ __launch_bounds__(256) void k_reduce(const float* __restrict__ hN,
    float* __restrict__ psum, float* __restrict__ pmax) {
  int lane = threadIdx.x & 63;
  int w = threadIdx.x >> 6;
  int b = blockIdx.x / CH;
  int chunk = blockIdx.x % CH;
  const int csz = (NN + CH - 1) / CH;  // 313
  int n0 = chunk * csz;
  int n1 = n0 + csz;
  if (n1 > NN) n1 = NN;
  float s = 0.f, m = -INFINITY;
  for (int n = n0 + w; n < n1; n += 4) {
    float v = hN[(size_t)n * 512 + b * 64 + lane];
    s += v;
    m = fmaxf(m, v);
  }
  __shared__ float ls[4][DD], lm[4][DD];
  ls[w][lane] = s;
  lm[w][lane] = m;
  __syncthreads();
  if (w == 0) {
    float ss = ls[0][lane] + ls[1][lane] + ls[2][lane] + ls[3][lane];
    float mm = fmaxf(fmaxf(lm[0][lane], lm[1][lane]),
                     fmaxf(lm[2][lane], lm[3][lane]));
    psum[((size_t)b * CH + chunk) * DD + lane] = ss;
    pmax[((size_t)b * CH + chunk) * DD + lane] = mm;
  }
}

// ---------------- final: reduce partials, graph_emb, 2-layer MLP head ----------------
__global__ __launch_bounds__(512) void k_final(const float* __restrict__ psum,
    const float* __restrict__ pmax, const float* __restrict__ Wh1,
    const float* __restrict__ bh1, const float* __restrict__ Wh2,
    const float* __restrict__ bh2, float* __restrict__ out) {
  __shared__ float emb[BB][2 * DD];
  __shared__ float hid[BB][DD];
  int t = threadIdx.x;  // 512 threads = 8 b * 64 d
  int b = t >> 6, d = t & 63;
  float s = 0.f, m = -INFINITY;
  for (int c = 0; c < CH; ++c) {
    s += psum[((size_t)b * CH + c) * DD + d];
    m = fmaxf(m, pmax[((size_t)b * CH + c) * DD + d]);
  }
  emb[b][d] = s * (1.0f / (float)NN);
  emb[b][DD + d] = m;
  __syncthreads();
  float acc = bh1[d];
#pragma unroll
  for (int k = 0; k < 2 * DD; ++k) acc = fmaf(emb[b][k], Wh1[k * DD + d], acc);
  hid[b][d] = acc > 0.f ? acc : 0.f;
  __syncthreads();
  if (d == 0) {
    float o = bh2[0];
    for (int j = 0; j < DD; ++j) o = fmaf(hid[b][j], Wh2[j], o);
    out[b] = o;
  }
}

extern "C" void kernel_launch(void* const* d_in, const int* in_sizes, int n_in,
                              void* d_out, int out_size, void* d_ws, size_t ws_size,
                              hipStream_t stream) {
  const float* x    = (const float*)d_in[0];
  const int*   ei   = (const int*)d_in[1];
  const float* Win  = (const float*)d_in[2];
  const float* bin  = (const float*)d_in[3];
  const float* Ws1  = (const float*)d_in[4];
  const float* Wm1  = (const float*)d_in[5];
  const float* bias1= (const float*)d_in[6];
  const float* g1   = (const float*)d_in[7];
  const float* be1  = (const float*)d_in[8];
  const float* Ws2  = (const float*)d_in[9];
  const float* Wm2  = (const float*)d_in[10];
  const float* bias2= (const float*)d_in[11];
  const float* g2   = (const float*)d_in[12];
  const float* be2  = (const float*)d_in[13];
  const float* Wh1  = (const float*)d_in[14];
  const float* bh1  = (const float*)d_in[15];
  const float* Wh2  = (const float*)d_in[16];
  const float* bh2  = (const float*)d_in[17];
  float* out = (float*)d_out;

  const int* src = ei;
  const int* dst = ei + EE;

  char* ws = (char*)d_ws;
  size_t off = 0;
  auto carve = [&](size_t bytes) {
    void* p = ws + off;
    off = (off + bytes + 255) & ~(size_t)255;
    return p;
  };
  const size_t hbytes = sizeof(float) * (size_t)ROWS * DD;  // 40.96 MB
  float* hA     = (float*)carve(hbytes);
  float* hB     = (float*)carve(hbytes);
  float* agg    = (float*)carve(hbytes);
  int*   cnt    = (int*)carve(sizeof(int) * NN);      // also reused as 'cur'
  int*   rowptr = (int*)carve(sizeof(int) * (NN + 1));
  int*   nbr    = (int*)carve(sizeof(int) * EE);
  float* invdeg = (float*)carve(sizeof(float) * NN);
  float* psum   = (float*)carve(sizeof(float) * (size_t)BB * CH * DD);
  float* pmax   = (float*)carve(sizeof(float) * (size_t)BB * CH * DD);

  const int NODE_BLOCKS = 512;  // 2048 waves = exactly 2 blocks/CU at bounds(256,2)
  const int NODE_WAVES = NODE_BLOCKS * 4;

  // encoder (node-major output)
  k_encoder<<<(NN * 512 / 4 + 255) / 256, 256, 0, stream>>>(x, Win, bin, hA);

  // CSR build (once; shared by both layers)
  hipMemsetAsync(cnt, 0, sizeof(int) * NN, stream);
  k_deg<<<(EE + 255) / 256, 256, 0, stream>>>(dst, cnt);
  k_invdeg<<<(NN + 255) / 256, 256, 0, stream>>>(cnt, invdeg);
  k_scan<<<1, 1024, 0, stream>>>(cnt, rowptr);
  hipMemsetAsync(cnt, 0, sizeof(int) * NN, stream);  // reuse as cursor
  k_fill<<<(EE + 255) / 256, 256, 0, stream>>>(src, dst, rowptr, cnt, nbr);

  // ---- layer 1 ----
  k_agg<<<(NN + 3) / 4, 256, 0, stream>>>(hA, rowptr, nbr, invdeg, agg);
  k_node<<<NODE_BLOCKS, 256, 0, stream>>>(hA, agg, Ws1, Wm1, bias1, g1, be1,
                                          hB, NODE_WAVES);

  // ---- layer 2 ----
  k_agg<<<(NN + 3) / 4, 256, 0, stream>>>(hB, rowptr, nbr, invdeg, agg);
  k_node<<<NODE_BLOCKS, 256, 0, stream>>>(hB, agg, Ws2, Wm2, bias2, g2, be2,
                                          hA, NODE_WAVES);

  // ---- readout + head ----
  k_reduce<<<BB * CH, 256, 0, stream>>>(hA, psum, pmax);
  k_final<<<1, 512, 0, stream>>>(psum, pmax, Wh1, bh1, Wh2, bh2, out);
}

// Round 5
// 372.919 us; speedup vs baseline: 1.6623x; 1.3646x over previous
//
#include <hip/hip_runtime.h>

#define BB 8
#define NN 20000
#define EE 320000
#define DD 64
#define ROWS (BB*NN)
#define TILES (ROWS/16)
#define EPS 1e-5f
#define CH 64  // readout chunks per batch

// Node-major layout: hN[n][b][d] -> flat n*512 + b*64 + d; row r=(n*8+b) is 64 contiguous floats.

typedef __attribute__((ext_vector_type(8))) short short8v;
typedef __attribute__((ext_vector_type(4))) float float4v;

__device__ __forceinline__ int bcasti(int v, int l) {
  return __builtin_amdgcn_readlane(v, l);
}
__device__ __forceinline__ unsigned short bf_rtn(float f) {
  unsigned int u = __float_as_uint(f);
  return (unsigned short)((u + 0x7FFFu + ((u >> 16) & 1u)) >> 16);
}
__device__ __forceinline__ float bf_to_f(unsigned short h) {
  return __uint_as_float(((unsigned int)h) << 16);
}
// split 8 floats into bf16 hi + bf16 lo fragments (bf16x3 scheme)
__device__ __forceinline__ void split8(float4 a, float4 b, short8v& hi, short8v& lo) {
  float x[8] = {a.x, a.y, a.z, a.w, b.x, b.y, b.z, b.w};
#pragma unroll
  for (int j = 0; j < 8; ++j) {
    unsigned short h = bf_rtn(x[j]);
    hi[j] = (short)h;
    lo[j] = (short)bf_rtn(x[j] - bf_to_f(h));
  }
}

// ---------------- encoder: hN = relu(x @ W_in + b_in), D_IN=1, float4 ----------------
__global__ __launch_bounds__(256) void k_encoder(const float* __restrict__ x,
    const float* __restrict__ Win, const float* __restrict__ bin,
    float* __restrict__ hN) {
  int idx = blockIdx.x * 256 + threadIdx.x;
  int g = idx * 4;
  if (g < NN * 512) {
    int n = g >> 9;
    int b = (g >> 6) & 7;
    int d0 = g & 63;
    float xv = x[(size_t)b * NN + n];
    float4 wv = *(const float4*)&Win[d0];
    float4 bv = *(const float4*)&bin[d0];
    float4 o;
    o.x = fmaf(xv, wv.x, bv.x); o.x = o.x > 0.f ? o.x : 0.f;
    o.y = fmaf(xv, wv.y, bv.y); o.y = o.y > 0.f ? o.y : 0.f;
    o.z = fmaf(xv, wv.z, bv.z); o.z = o.z > 0.f ? o.z : 0.f;
    o.w = fmaf(xv, wv.w, bv.w); o.w = o.w > 0.f ? o.w : 0.f;
    *(float4*)&hN[g] = o;
  }
}

// ---------------- degree ----------------
__global__ __launch_bounds__(256) void k_deg(const int* __restrict__ dst,
                                             int* __restrict__ cnt) {
  int e = blockIdx.x * 256 + threadIdx.x;
  if (e < EE) atomicAdd(&cnt[dst[e]], 1);
}

__global__ __launch_bounds__(256) void k_invdeg(const int* __restrict__ cnt,
                                                float* __restrict__ invdeg) {
  int n = blockIdx.x * 256 + threadIdx.x;
  if (n < NN) {
    int c = cnt[n];
    invdeg[n] = 1.0f / (float)(c > 1 ? c : 1);
  }
}

// ---------------- exclusive scan of cnt -> rowptr (single block) ----------------
__global__ __launch_bounds__(1024) void k_scan(const int* __restrict__ cnt,
                                               int* __restrict__ rowptr) {
  __shared__ int part[1024];
  int t = threadIdx.x;
  const int PER = (NN + 1023) / 1024;  // 20
  int base = t * PER;
  int s = 0;
#pragma unroll
  for (int i = 0; i < PER; ++i) {
    int idx = base + i;
    s += (idx < NN) ? cnt[idx] : 0;
  }
  part[t] = s;
  __syncthreads();
  for (int off = 1; off < 1024; off <<= 1) {
    int v = (t >= off) ? part[t - off] : 0;
    __syncthreads();
    part[t] += v;
    __syncthreads();
  }
  int run = (t > 0) ? part[t - 1] : 0;
#pragma unroll
  for (int i = 0; i < PER; ++i) {
    int idx = base + i;
    if (idx <= NN) rowptr[idx] = run;
    run += (idx < NN) ? cnt[idx] : 0;
  }
}

// ---------------- fill CSR buckets ----------------
__global__ __launch_bounds__(256) void k_fill(const int* __restrict__ src,
    const int* __restrict__ dst, const int* __restrict__ rowptr,
    int* __restrict__ cur, int* __restrict__ nbr) {
  int e = blockIdx.x * 256 + threadIdx.x;
  if (e < EE) {
    int t = dst[e];
    int pos = rowptr[t] + atomicAdd(&cur[t], 1);
    nbr[pos] = src[e];
  }
}

// ---------------- pull aggregation, node-major, 4-edge unroll ----------------
__global__ __launch_bounds__(256) void k_agg(const float* __restrict__ hN,
    const int* __restrict__ rowptr, const int* __restrict__ nbr,
    const float* __restrict__ invdeg, float* __restrict__ aggN) {
  int wid = (blockIdx.x * 256 + threadIdx.x) >> 6;  // wave per node
  int lane = threadIdx.x & 63;
  if (wid >= NN) return;
  int n = wid;
  int s0 = rowptr[n], s1 = rowptr[n + 1];
  float4 accLo = {0.f, 0.f, 0.f, 0.f}, accHi = {0.f, 0.f, 0.f, 0.f};
  for (int base = s0; base < s1; base += 64) {
    int m = s1 - base;
    if (m > 64) m = 64;
    int idxv = (base + lane < s1) ? nbr[base + lane] : 0;
    int j = 0;
    for (; j + 4 <= m; j += 4) {
      int sA = bcasti(idxv, j),     sB = bcasti(idxv, j + 1);
      int sC = bcasti(idxv, j + 2), sD = bcasti(idxv, j + 3);
      const float4* pA = (const float4*)(hN + (size_t)sA * 512);
      const float4* pB = (const float4*)(hN + (size_t)sB * 512);
      const float4* pC = (const float4*)(hN + (size_t)sC * 512);
      const float4* pD = (const float4*)(hN + (size_t)sD * 512);
      float4 a0 = pA[lane], a1 = pA[lane + 64];
      float4 b0 = pB[lane], b1 = pB[lane + 64];
      float4 c0 = pC[lane], c1 = pC[lane + 64];
      float4 d0 = pD[lane], d1 = pD[lane + 64];
      accLo.x += (a0.x + b0.x) + (c0.x + d0.x);
      accLo.y += (a0.y + b0.y) + (c0.y + d0.y);
      accLo.z += (a0.z + b0.z) + (c0.z + d0.z);
      accLo.w += (a0.w + b0.w) + (c0.w + d0.w);
      accHi.x += (a1.x + b1.x) + (c1.x + d1.x);
      accHi.y += (a1.y + b1.y) + (c1.y + d1.y);
      accHi.z += (a1.z + b1.z) + (c1.z + d1.z);
      accHi.w += (a1.w + b1.w) + (c1.w + d1.w);
    }
    for (; j < m; ++j) {
      int sA = bcasti(idxv, j);
      const float4* pA = (const float4*)(hN + (size_t)sA * 512);
      float4 a0 = pA[lane], a1 = pA[lane + 64];
      accLo.x += a0.x; accLo.y += a0.y; accLo.z += a0.z; accLo.w += a0.w;
      accHi.x += a1.x; accHi.y += a1.y; accHi.z += a1.z; accHi.w += a1.w;
    }
  }
  float iv = invdeg[n];
  accLo.x *= iv; accLo.y *= iv; accLo.z *= iv; accLo.w *= iv;
  accHi.x *= iv; accHi.y *= iv; accHi.z *= iv; accHi.w *= iv;
  float4* q = (float4*)(aggN + (size_t)n * 512);
  q[lane] = accLo;
  q[lane + 64] = accHi;
}

// ---------------- MFMA node update: z = h + relu(h@Ws + agg@Wm + bias); LN ----------------
// bf16x3 split GEMM on 16-row tiles, one tile per wave iteration.
// A-frag (16x16x32 bf16): lane holds A[row=l&15][k=(l>>4)*8+j], j=0..7.
// B-frag: lane holds B[k=(l>>4)*8+j][col=l&15].
// C/D:    lane,reg j -> row=(l>>4)*4+j, col=l&15  (m89/m91-verified).
// Split weights staged in LDS in frag order: 16B/lane ds_read_b128, conflict-free.
__global__ __launch_bounds__(256) void k_node_mfma(const float* __restrict__ hN,
    const float* __restrict__ aggN, const float* __restrict__ Ws,
    const float* __restrict__ Wm, const float* __restrict__ bias,
    const float* __restrict__ g, const float* __restrict__ be,
    float* __restrict__ outN, int nwaves_total) {
  __shared__ unsigned short ldsw[16384];  // [m][p][c][t][lane][8] = 32 KB
  int tid = threadIdx.x;
  int lane = tid & 63;
  int cidx = lane & 15;
  int grp = lane >> 4;

  // ---- stage split weights into LDS (once per block) ----
  for (int m = 0; m < 2; ++m) {
    const float* W = m ? Wm : Ws;
    for (int p = 0; p < 2; ++p) {
      for (int slot = tid; slot < 512; slot += 256) {
        int c = slot >> 8;
        int t = (slot >> 6) & 3;
        int l = slot & 63;
        int k0 = c * 32 + (l >> 4) * 8;
        int col = t * 16 + (l & 15);
        short8v o;
#pragma unroll
        for (int i = 0; i < 8; ++i) {
          float w = W[(k0 + i) * DD + col];
          unsigned short h16 = bf_rtn(w);
          o[i] = p ? (short)bf_rtn(w - bf_to_f(h16)) : (short)h16;
        }
        int off = (((m * 2 + p) * 2 + c) * 4 + t) * 512 + l * 8;
        *(short8v*)&ldsw[off] = o;
      }
    }
  }
  __syncthreads();

  // per-wave hoisted epilogue constants (col = t*16 + cidx)
  float bias_c[4], gam_c[4], bet_c[4];
#pragma unroll
  for (int t = 0; t < 4; ++t) {
    int c = t * 16 + cidx;
    bias_c[t] = bias[c];
    gam_c[t] = g[c];
    bet_c[t] = be[c];
  }

  int gwave = blockIdx.x * 4 + (tid >> 6);
  for (int tile = gwave; tile < TILES; tile += nwaves_total) {
    int r0 = tile * 16;
    // ---- A fragments: h and agg rows, split hi/lo, 2 K-chunks ----
    const float* hp = hN + (size_t)(r0 + cidx) * DD + grp * 8;
    const float* ap = aggN + (size_t)(r0 + cidx) * DD + grp * 8;
    short8v ah_hi[2], ah_lo[2], am_hi[2], am_lo[2];
    {
      float4 x0 = *(const float4*)(hp);
      float4 x1 = *(const float4*)(hp + 4);
      float4 x2 = *(const float4*)(hp + 32);
      float4 x3 = *(const float4*)(hp + 36);
      split8(x0, x1, ah_hi[0], ah_lo[0]);
      split8(x2, x3, ah_hi[1], ah_lo[1]);
      float4 y0 = *(const float4*)(ap);
      float4 y1 = *(const float4*)(ap + 4);
      float4 y2 = *(const float4*)(ap + 32);
      float4 y3 = *(const float4*)(ap + 36);
      split8(y0, y1, am_hi[0], am_lo[0]);
      split8(y2, y3, am_hi[1], am_lo[1]);
    }
    // ---- MFMA accumulation over 4 N-tiles x 2 K-chunks, bf16x3 ----
    float4v acc[4];
#pragma unroll
    for (int t = 0; t < 4; ++t) acc[t] = (float4v){0.f, 0.f, 0.f, 0.f};
#pragma unroll
    for (int t = 0; t < 4; ++t) {
#pragma unroll
      for (int c = 0; c < 2; ++c) {
        const short8v bsh = *(const short8v*)&ldsw[((0 * 2 + c) * 4 + t) * 512 + lane * 8];
        const short8v bsl = *(const short8v*)&ldsw[((1 * 2 + c) * 4 + t) * 512 + lane * 8];
        const short8v bmh = *(const short8v*)&ldsw[((2 * 2 + c) * 4 + t) * 512 + lane * 8];
        const short8v bml = *(const short8v*)&ldsw[((3 * 2 + c) * 4 + t) * 512 + lane * 8];
        acc[t] = __builtin_amdgcn_mfma_f32_16x16x32_bf16(ah_hi[c], bsh, acc[t], 0, 0, 0);
        acc[t] = __builtin_amdgcn_mfma_f32_16x16x32_bf16(ah_lo[c], bsh, acc[t], 0, 0, 0);
        acc[t] = __builtin_amdgcn_mfma_f32_16x16x32_bf16(ah_hi[c], bsl, acc[t], 0, 0, 0);
        acc[t] = __builtin_amdgcn_mfma_f32_16x16x32_bf16(am_hi[c], bmh, acc[t], 0, 0, 0);
        acc[t] = __builtin_amdgcn_mfma_f32_16x16x32_bf16(am_lo[c], bmh, acc[t], 0, 0, 0);
        acc[t] = __builtin_amdgcn_mfma_f32_16x16x32_bf16(am_hi[c], bml, acc[t], 0, 0, 0);
      }
    }
    // ---- epilogue: residual + relu + LayerNorm, rows r0+grp*4+j ----
#pragma unroll
    for (int j = 0; j < 4; ++j) {
      int row = r0 + grp * 4 + j;
      const float* hr = hN + (size_t)row * DD;
      float zz[4];
      float part = 0.f;
#pragma unroll
      for (int t = 0; t < 4; ++t) {
        float hv = hr[t * 16 + cidx];
        float v = acc[t][j] + bias_c[t];
        v = v > 0.f ? v : 0.f;
        zz[t] = hv + v;
        part += zz[t];
      }
      part += __shfl_xor(part, 1);
      part += __shfl_xor(part, 2);
      part += __shfl_xor(part, 4);
      part += __shfl_xor(part, 8);
      float mu = part * (1.0f / 64.0f);
      float vs = 0.f;
#pragma unroll
      for (int t = 0; t < 4; ++t) {
        float d = zz[t] - mu;
        vs += d * d;
      }
      vs += __shfl_xor(vs, 1);
      vs += __shfl_xor(vs, 2);
      vs += __shfl_xor(vs, 4);
      vs += __shfl_xor(vs, 8);
      float inv = rsqrtf(vs * (1.0f / 64.0f) + EPS);
#pragma unroll
      for (int t = 0; t < 4; ++t) {
        outN[(size_t)row * DD + t * 16 + cidx] =
            fmaf(gam_c[t] * (zz[t] - mu), inv, bet_c[t]);
      }
    }
  }
}

// ---------------- readout partials ----------------
__global__ __launch_bounds__(256) void k_reduce(const float* __restrict__ hN,
    float* __restrict__ psum, float* __restrict__ pmax) {
  int lane = threadIdx.x & 63;
  int w = threadIdx.x >> 6;
  int b = blockIdx.x / CH;
  int chunk = blockIdx.x % CH;
  const int csz = (NN + CH - 1) / CH;  // 313
  int n0 = chunk * csz;
  int n1 = n0 + csz;
  if (n1 > NN) n1 = NN;
  float s = 0.f, m = -INFINITY;
  for (int n = n0 + w; n < n1; n += 4) {
    float v = hN[(size_t)n * 512 + b * 64 + lane];
    s += v;
    m = fmaxf(m, v);
  }
  __shared__ float ls[4][DD], lm[4][DD];
  ls[w][lane] = s;
  lm[w][lane] = m;
  __syncthreads();
  if (w == 0) {
    float ss = ls[0][lane] + ls[1][lane] + ls[2][lane] + ls[3][lane];
    float mm = fmaxf(fmaxf(lm[0][lane], lm[1][lane]),
                     fmaxf(lm[2][lane], lm[3][lane]));
    psum[((size_t)b * CH + chunk) * DD + lane] = ss;
    pmax[((size_t)b * CH + chunk) * DD + lane] = mm;
  }
}

// ---------------- final: graph_emb + MLP head ----------------
__global__ __launch_bounds__(512) void k_final(const float* __restrict__ psum,
    const float* __restrict__ pmax, const float* __restrict__ Wh1,
    const float* __restrict__ bh1, const float* __restrict__ Wh2,
    const float* __restrict__ bh2, float* __restrict__ out) {
  __shared__ float emb[BB][2 * DD];
  __shared__ float hid[BB][DD];
  int t = threadIdx.x;
  int b = t >> 6, d = t & 63;
  float s = 0.f, m = -INFINITY;
  for (int c = 0; c < CH; ++c) {
    s += psum[((size_t)b * CH + c) * DD + d];
    m = fmaxf(m, pmax[((size_t)b * CH + c) * DD + d]);
  }
  emb[b][d] = s * (1.0f / (float)NN);
  emb[b][DD + d] = m;
  __syncthreads();
  float acc = bh1[d];
#pragma unroll
  for (int k = 0; k < 2 * DD; ++k) acc = fmaf(emb[b][k], Wh1[k * DD + d], acc);
  hid[b][d] = acc > 0.f ? acc : 0.f;
  __syncthreads();
  if (d == 0) {
    float o = bh2[0];
    for (int j = 0; j < DD; ++j) o = fmaf(hid[b][j], Wh2[j], o);
    out[b] = o;
  }
}

extern "C" void kernel_launch(void* const* d_in, const int* in_sizes, int n_in,
                              void* d_out, int out_size, void* d_ws, size_t ws_size,
                              hipStream_t stream) {
  const float* x    = (const float*)d_in[0];
  const int*   ei   = (const int*)d_in[1];
  const float* Win  = (const float*)d_in[2];
  const float* bin  = (const float*)d_in[3];
  const float* Ws1  = (const float*)d_in[4];
  const float* Wm1  = (const float*)d_in[5];
  const float* bias1= (const float*)d_in[6];
  const float* g1   = (const float*)d_in[7];
  const float* be1  = (const float*)d_in[8];
  const float* Ws2  = (const float*)d_in[9];
  const float* Wm2  = (const float*)d_in[10];
  const float* bias2= (const float*)d_in[11];
  const float* g2   = (const float*)d_in[12];
  const float* be2  = (const float*)d_in[13];
  const float* Wh1  = (const float*)d_in[14];
  const float* bh1  = (const float*)d_in[15];
  const float* Wh2  = (const float*)d_in[16];
  const float* bh2  = (const float*)d_in[17];
  float* out = (float*)d_out;

  const int* src = ei;
  const int* dst = ei + EE;

  char* ws = (char*)d_ws;
  size_t off = 0;
  auto carve = [&](size_t bytes) {
    void* p = ws + off;
    off = (off + bytes + 255) & ~(size_t)255;
    return p;
  };
  const size_t hbytes = sizeof(float) * (size_t)ROWS * DD;  // 40.96 MB
  float* hA     = (float*)carve(hbytes);
  float* hB     = (float*)carve(hbytes);
  float* agg    = (float*)carve(hbytes);
  int*   cnt    = (int*)carve(sizeof(int) * NN);      // reused as 'cur'
  int*   rowptr = (int*)carve(sizeof(int) * (NN + 1));
  int*   nbr    = (int*)carve(sizeof(int) * EE);
  float* invdeg = (float*)carve(sizeof(float) * NN);
  float* psum   = (float*)carve(sizeof(float) * (size_t)BB * CH * DD);
  float* pmax   = (float*)carve(sizeof(float) * (size_t)BB * CH * DD);

  const int NODE_BLOCKS = 512;
  const int NODE_WAVES = NODE_BLOCKS * 4;

  // encoder (node-major output)
  k_encoder<<<(NN * 512 / 4 + 255) / 256, 256, 0, stream>>>(x, Win, bin, hA);

  // CSR build (once; shared by both layers)
  hipMemsetAsync(cnt, 0, sizeof(int) * NN, stream);
  k_deg<<<(EE + 255) / 256, 256, 0, stream>>>(dst, cnt);
  k_invdeg<<<(NN + 255) / 256, 256, 0, stream>>>(cnt, invdeg);
  k_scan<<<1, 1024, 0, stream>>>(cnt, rowptr);
  hipMemsetAsync(cnt, 0, sizeof(int) * NN, stream);  // reuse as cursor
  k_fill<<<(EE + 255) / 256, 256, 0, stream>>>(src, dst, rowptr, cnt, nbr);

  // ---- layer 1 ----
  k_agg<<<(NN + 3) / 4, 256, 0, stream>>>(hA, rowptr, nbr, invdeg, agg);
  k_node_mfma<<<NODE_BLOCKS, 256, 0, stream>>>(hA, agg, Ws1, Wm1, bias1, g1,
                                               be1, hB, NODE_WAVES);

  // ---- layer 2 ----
  k_agg<<<(NN + 3) / 4, 256, 0, stream>>>(hB, rowptr, nbr, invdeg, agg);
  k_node_mfma<<<NODE_BLOCKS, 256, 0, stream>>>(hB, agg, Ws2, Wm2, bias2, g2,
                                               be2, hA, NODE_WAVES);

  // ---- readout + head ----
  k_reduce<<<BB * CH, 256, 0, stream>>>(hA, psum, pmax);
  k_final<<<1, 512, 0, stream>>>(psum, pmax, Wh1, bh1, Wh2, bh2, out);
}